// Round 3
// baseline (293.095 us; speedup 1.0000x reference)
//
#include <hip/hip_runtime.h>

// GradientInputLayer: B=64, C=2, L=64, N=16, BIN=360//16=22, EPS=1e-5
// x: (64, 2*64^3) f32 in {0,1}; out: (64,2,16,16) f32
//
// ws layout: [0, 262144)        uint8 bin table tab[i*4096 + j*64 + k]
//            [262144, 393216)   float g[128*256] accumulator (pair-major)
//            [393216, 393220)   unsigned int completion counter

#define BINS_PAD 80   // real bins are 0..68 (ax,az in 0..4); 69 = flush sentinel

typedef float vf4 __attribute__((ext_vector_type(4)));

__global__ __launch_bounds__(256)
void bin_table_kernel(unsigned char* __restrict__ tab, float* __restrict__ g,
                      unsigned int* __restrict__ counter) {
    int v = blockIdx.x * 256 + threadIdx.x;          // 0..262143
    int i = v >> 12, j = (v >> 6) & 63, k = v & 63;
    double xc2 = (double)(j * j + k * k);            // x_comp^2
    double zc2 = (double)(i * i + j * j);            // z_comp^2
    double i2  = (double)(i * i);
    double k2  = (double)(k * k);
    // tan^2 of 22/44/66/88 degrees; fold at compile time in double.
    const double T1 = 0.4040262258351568  * 0.4040262258351568;
    const double T2 = 0.9656887748070740  * 0.9656887748070740;
    const double T3 = 2.2460367739042161  * 2.2460367739042161;
    const double T4 = 28.636253282915602  * 28.636253282915602;
    // ax = floor(atan2(xc, i)*deg/22) == #{m : xc^2 > i^2 tan^2(22m)}; strict >
    // handles every atan2(0,*)/atan2(*,0) edge case exactly (verified absmax 0.0).
    int ax = (xc2 > i2 * T1) + (xc2 > i2 * T2) + (xc2 > i2 * T3) + (xc2 > i2 * T4);
    int az = (k2 > zc2 * T1) + (k2 > zc2 * T2) + (k2 > zc2 * T3) + (k2 > zc2 * T4);
    tab[v] = (unsigned char)(ax * 16 + az);
    if (v < 32768) g[v] = 0.0f;                      // zero accumulator (ws is poisoned)
    if (v == 0)    *counter = 0u;
}

// 256-thread blocks (4 waves); block = (pair p, 4 i-slabs), wave w owns slab i.
// Per-lane run-length accumulation (cur_bin, acc) over 4-consecutive-k chunks;
// LDS-hist flush only on bin change; one <=80-bin global-atomic flush per block.
// The LAST block to finish (device-scope counter) computes the group-norm and
// writes the output — removes the standalone 1-block norm kernel + launch gap.
__global__ __launch_bounds__(256)
void scatter_norm_kernel(const vf4* __restrict__ x4,
                         const unsigned int* __restrict__ tabu,
                         float* __restrict__ g,
                         unsigned int* __restrict__ counter,
                         const float* __restrict__ gamma,
                         const float* __restrict__ beta,
                         float* __restrict__ out) {
    __shared__ float hist[BINS_PAD];
    __shared__ unsigned int last_flag;
    __shared__ double red[4][4];
    __shared__ float coef[4];

    int tid = threadIdx.x;
    int p   = blockIdx.x >> 4;               // (b,c) pair 0..127
    int w   = tid >> 6;                      // wave 0..3
    int t   = tid & 63;                      // lane
    int i   = (blockIdx.x & 15) * 4 + w;     // i-slab 0..63
    if (tid < BINS_PAD) hist[tid] = 0.0f;
    __syncthreads();

    const vf4*          xs = x4   + (size_t)p * 65536 + (size_t)i * 1024;
    const unsigned int* ts = tabu + i * 1024;

    int thi = t >> 4;                 // j sub-index 0..3
    int k0  = (t & 15) * 4;           // this lane's k base (lane-constant)
    float kk0 = (float)(k0 * k0);
    float kk1 = (float)((k0 + 1) * (k0 + 1));
    float kk2 = (float)((k0 + 2) * (k0 + 2));
    float kk3 = (float)((k0 + 3) * (k0 + 3));
    int i2 = i * i;

    float acc = 0.0f;
    int   cur = 69;                   // sentinel bin (never produced; stays ~0)

    #pragma unroll 4
    for (int m = 0; m < 16; ++m) {
        vf4          xv = __builtin_nontemporal_load(&xs[m * 64 + t]);  // x is stream-once
        unsigned int u  = ts[m * 64 + t];                               // tab stays L2-hot
        int   j   = m * 4 + thi;      // j-line within slab
        float r2f = (float)(i2 + j * j);
        {   int b = u & 255;
            float val = xv.x * sqrtf(r2f + kk0);
            if (b != cur) { atomicAdd(&hist[cur], acc); cur = b; acc = val; }
            else          { acc += val; } }
        {   int b = (u >> 8) & 255;
            float val = xv.y * sqrtf(r2f + kk1);
            if (b != cur) { atomicAdd(&hist[cur], acc); cur = b; acc = val; }
            else          { acc += val; } }
        {   int b = (u >> 16) & 255;
            float val = xv.z * sqrtf(r2f + kk2);
            if (b != cur) { atomicAdd(&hist[cur], acc); cur = b; acc = val; }
            else          { acc += val; } }
        {   int b = (u >> 24);
            float val = xv.w * sqrtf(r2f + kk3);
            if (b != cur) { atomicAdd(&hist[cur], acc); cur = b; acc = val; }
            else          { acc += val; } }
    }
    atomicAdd(&hist[cur], acc);
    __syncthreads();

    if (tid < BINS_PAD) {
        float hv = hist[tid];
        if (hv != 0.0f) atomicAdd(&g[p * 256 + tid], hv);
    }
    __syncthreads();                  // all flush atomics issued + drained (barrier waits vmcnt)

    if (tid == 0) {
        __threadfence();              // release: g atomics visible before counter bump
        unsigned int old = atomicAdd(counter, 1u);
        last_flag = (old == 2047u);
    }
    __syncthreads();
    if (!last_flag) return;

    // ---- last block: per-channel mean/var over (B,N,N)=16384 values, then write out ----
    __threadfence();                  // acquire: see every block's g atomics
    const vf4* g4 = (const vf4*)g;    // 8192 float4s; channel = (idx4 >> 6) & 1
    double s0 = 0.0, s1 = 0.0, q0 = 0.0, q1 = 0.0;
    #pragma unroll
    for (int n = 0; n < 32; ++n) {
        int idx = tid + n * 256;
        vf4 v = g4[idx];
        double a = v.x, b = v.y, c = v.z, d = v.w;
        double sum = a + b + c + d;
        double sq  = a * a + b * b + c * c + d * d;
        if ((idx >> 6) & 1) { s1 += sum; q1 += sq; }
        else                { s0 += sum; q0 += sq; }
    }
    #pragma unroll
    for (int off = 32; off > 0; off >>= 1) {
        s0 += __shfl_down(s0, off);
        s1 += __shfl_down(s1, off);
        q0 += __shfl_down(q0, off);
        q1 += __shfl_down(q1, off);
    }
    if (t == 0) { red[w][0] = s0; red[w][1] = s1; red[w][2] = q0; red[w][3] = q1; }
    __syncthreads();
    if (tid == 0) {
        double S0 = 0, S1 = 0, Q0 = 0, Q1 = 0;
        for (int wv = 0; wv < 4; ++wv) {
            S0 += red[wv][0]; S1 += red[wv][1]; Q0 += red[wv][2]; Q1 += red[wv][3];
        }
        const double inv_n = 1.0 / 16384.0;
        double m0 = S0 * inv_n, m1 = S1 * inv_n;
        double v0 = Q0 * inv_n - m0 * m0;
        double v1 = Q1 * inv_n - m1 * m1;
        double r0 = 1.0 / sqrt(v0 + 1e-5);
        double r1 = 1.0 / sqrt(v1 + 1e-5);
        float g0 = gamma[0], g1 = gamma[1], b0 = beta[0], b1 = beta[1];
        coef[0] = (float)r0 * g0;
        coef[1] = (float)r1 * g1;
        coef[2] = b0 - (float)(m0 * r0) * g0;
        coef[3] = b1 - (float)(m1 * r1) * g1;
    }
    __syncthreads();
    float sc0 = coef[0], sc1 = coef[1], sh0 = coef[2], sh1 = coef[3];
    vf4* out4 = (vf4*)out;
    #pragma unroll
    for (int n = 0; n < 32; ++n) {
        int idx = tid + n * 256;
        vf4 v = g4[idx];              // L2/L1-hot second read
        int c = (idx >> 6) & 1;
        float sc = c ? sc1 : sc0, sh = c ? sh1 : sh0;
        vf4 o;
        o.x = v.x * sc + sh; o.y = v.y * sc + sh;
        o.z = v.z * sc + sh; o.w = v.w * sc + sh;
        out4[idx] = o;
    }
}

extern "C" void kernel_launch(void* const* d_in, const int* in_sizes, int n_in,
                              void* d_out, int out_size, void* d_ws, size_t ws_size,
                              hipStream_t stream) {
    const float* x     = (const float*)d_in[0];
    const float* gamma = (const float*)d_in[1];
    const float* beta  = (const float*)d_in[2];
    float* out = (float*)d_out;

    unsigned char* tab     = (unsigned char*)d_ws;
    float*         g       = (float*)((char*)d_ws + 262144);
    unsigned int*  counter = (unsigned int*)((char*)d_ws + 393216);

    bin_table_kernel<<<1024, 256, 0, stream>>>(tab, g, counter);
    scatter_norm_kernel<<<2048, 256, 0, stream>>>((const vf4*)x, (const unsigned int*)tab,
                                                  g, counter, gamma, beta, out);
}

// Round 4
// 207.754 us; speedup vs baseline: 1.4108x; 1.4108x over previous
//
#include <hip/hip_runtime.h>

// GradientInputLayer: B=64, C=2, L=64, N=16, BIN=360//16=22, EPS=1e-5
// x: (64, 2*64^3) f32 in {0,1}; out: (64,2,16,16) f32
//
// ws layout: [0, 262144)      uint8 bin table tab[i*4096 + j*64 + k]
//            [262144, 393216) float g[128*256] accumulator (pair-major)
//
// R3 lesson: NO device-scope fences in the per-block path (threadfence -> L2
// writeback per block serialized everything, 137us). NO nontemporal loads on x.

#define BINS_PAD 80   // real bins are 0..68 (ax,az in 0..4); 69 = flush sentinel

__global__ __launch_bounds__(256)
void bin_table_kernel(unsigned char* __restrict__ tab, float* __restrict__ g) {
    int v = blockIdx.x * 256 + threadIdx.x;          // 0..262143
    int i = v >> 12, j = (v >> 6) & 63, k = v & 63;
    double xc2 = (double)(j * j + k * k);            // x_comp^2
    double zc2 = (double)(i * i + j * j);            // z_comp^2
    double i2  = (double)(i * i);
    double k2  = (double)(k * k);
    // tan^2 of 22/44/66/88 degrees; fold at compile time in double.
    const double T1 = 0.4040262258351568  * 0.4040262258351568;
    const double T2 = 0.9656887748070740  * 0.9656887748070740;
    const double T3 = 2.2460367739042161  * 2.2460367739042161;
    const double T4 = 28.636253282915602  * 28.636253282915602;
    // ax = floor(atan2(xc, i)*deg/22) == #{m : xc^2 > i^2 tan^2(22m)}; strict >
    // handles every atan2(0,*)/atan2(*,0) edge case exactly (verified absmax 0.0).
    int ax = (xc2 > i2 * T1) + (xc2 > i2 * T2) + (xc2 > i2 * T3) + (xc2 > i2 * T4);
    int az = (k2 > zc2 * T1) + (k2 > zc2 * T2) + (k2 > zc2 * T3) + (k2 > zc2 * T4);
    tab[v] = (unsigned char)(ax * 16 + az);
    if (v < 32768) g[v] = 0.0f;                      // zero accumulator (ws is poisoned)
}

// 256-thread blocks (4 waves); block = (pair p, 4 i-slabs), wave w owns slab i.
// Per-lane run-length accumulation (cur_bin, acc) over 4-consecutive-k chunks;
// WAVE-PRIVATE LDS hist (removes inter-wave same-address atomic serialization);
// one <=80-bin global-atomic flush per block.
__global__ __launch_bounds__(256)
void scatter_kernel(const float4* __restrict__ x4,
                    const unsigned int* __restrict__ tabu,
                    float* __restrict__ g) {
    __shared__ float hist[4][BINS_PAD];
    int tid = threadIdx.x;
    int p   = blockIdx.x >> 4;               // (b,c) pair 0..127
    int w   = tid >> 6;                      // wave 0..3
    int t   = tid & 63;                      // lane
    int i   = (blockIdx.x & 15) * 4 + w;     // i-slab 0..63
    #pragma unroll
    for (int n = tid; n < 4 * BINS_PAD; n += 256) ((float*)hist)[n] = 0.0f;
    __syncthreads();

    float* whist = hist[w];

    const float4*       xs = x4   + (size_t)p * 65536 + (size_t)i * 1024;
    const unsigned int* ts = tabu + i * 1024;

    int thi = t >> 4;                 // j sub-index 0..3
    int k0  = (t & 15) * 4;           // this lane's k base (lane-constant)
    float kk0 = (float)(k0 * k0);
    float kk1 = (float)((k0 + 1) * (k0 + 1));
    float kk2 = (float)((k0 + 2) * (k0 + 2));
    float kk3 = (float)((k0 + 3) * (k0 + 3));
    int i2 = i * i;

    float acc = 0.0f;
    int   cur = 69;                   // sentinel bin (never produced; stays ~0)

    #pragma unroll 4
    for (int m = 0; m < 16; ++m) {
        float4       xv = xs[m * 64 + t];
        unsigned int u  = ts[m * 64 + t];
        int   j   = m * 4 + thi;      // j-line within slab
        float r2f = (float)(i2 + j * j);
        {   int b = u & 255;
            float val = xv.x * sqrtf(r2f + kk0);
            if (b != cur) { atomicAdd(&whist[cur], acc); cur = b; acc = val; }
            else          { acc += val; } }
        {   int b = (u >> 8) & 255;
            float val = xv.y * sqrtf(r2f + kk1);
            if (b != cur) { atomicAdd(&whist[cur], acc); cur = b; acc = val; }
            else          { acc += val; } }
        {   int b = (u >> 16) & 255;
            float val = xv.z * sqrtf(r2f + kk2);
            if (b != cur) { atomicAdd(&whist[cur], acc); cur = b; acc = val; }
            else          { acc += val; } }
        {   int b = (u >> 24);
            float val = xv.w * sqrtf(r2f + kk3);
            if (b != cur) { atomicAdd(&whist[cur], acc); cur = b; acc = val; }
            else          { acc += val; } }
    }
    atomicAdd(&whist[cur], acc);
    __syncthreads();

    if (tid < BINS_PAD) {
        float hv = hist[0][tid] + hist[1][tid] + hist[2][tid] + hist[3][tid];
        if (hv != 0.0f) atomicAdd(&g[p * 256 + tid], hv);
    }
}

// Single block: per-channel mean/var over (B, N, N) = 16384 values in double,
// then fused scale/shift write of all 32768 outputs.
__global__ __launch_bounds__(1024)
void norm_kernel(const float* __restrict__ g,
                 const float* __restrict__ gamma,
                 const float* __restrict__ beta,
                 float* __restrict__ out) {
    __shared__ double red[16][4];
    __shared__ float  coef[4];        // sc0, sc1, sh0, sh1
    int t = threadIdx.x;
    float vals[32];
    double s0 = 0.0, s1 = 0.0, q0 = 0.0, q1 = 0.0;
    #pragma unroll
    for (int n = 0; n < 32; ++n) {
        int idx = t + n * 1024;
        float v = g[idx];
        vals[n] = v;
        double vd = (double)v;
        if ((idx >> 8) & 1) { s1 += vd; q1 += vd * vd; }
        else                { s0 += vd; q0 += vd * vd; }
    }
    #pragma unroll
    for (int off = 32; off > 0; off >>= 1) {
        s0 += __shfl_down(s0, off);
        s1 += __shfl_down(s1, off);
        q0 += __shfl_down(q0, off);
        q1 += __shfl_down(q1, off);
    }
    int wave = t >> 6;
    if ((t & 63) == 0) {
        red[wave][0] = s0; red[wave][1] = s1; red[wave][2] = q0; red[wave][3] = q1;
    }
    __syncthreads();
    if (t == 0) {
        double S0 = 0, S1 = 0, Q0 = 0, Q1 = 0;
        for (int wv = 0; wv < 16; ++wv) {
            S0 += red[wv][0]; S1 += red[wv][1]; Q0 += red[wv][2]; Q1 += red[wv][3];
        }
        const double inv_n = 1.0 / 16384.0;
        double m0 = S0 * inv_n, m1 = S1 * inv_n;
        double v0 = Q0 * inv_n - m0 * m0;
        double v1 = Q1 * inv_n - m1 * m1;
        double r0 = 1.0 / sqrt(v0 + 1e-5);
        double r1 = 1.0 / sqrt(v1 + 1e-5);
        float g0 = gamma[0], g1 = gamma[1], b0 = beta[0], b1 = beta[1];
        coef[0] = (float)r0 * g0;
        coef[1] = (float)r1 * g1;
        coef[2] = b0 - (float)(m0 * r0) * g0;
        coef[3] = b1 - (float)(m1 * r1) * g1;
    }
    __syncthreads();
    float sc0 = coef[0], sc1 = coef[1], sh0 = coef[2], sh1 = coef[3];
    #pragma unroll
    for (int n = 0; n < 32; ++n) {
        int idx = t + n * 1024;
        int c = (idx >> 8) & 1;
        out[idx] = vals[n] * (c ? sc1 : sc0) + (c ? sh1 : sh0);
    }
}

extern "C" void kernel_launch(void* const* d_in, const int* in_sizes, int n_in,
                              void* d_out, int out_size, void* d_ws, size_t ws_size,
                              hipStream_t stream) {
    const float* x     = (const float*)d_in[0];
    const float* gamma = (const float*)d_in[1];
    const float* beta  = (const float*)d_in[2];
    float* out = (float*)d_out;

    unsigned char* tab = (unsigned char*)d_ws;
    float*         g   = (float*)((char*)d_ws + 262144);

    bin_table_kernel<<<1024, 256, 0, stream>>>(tab, g);
    scatter_kernel<<<2048, 256, 0, stream>>>((const float4*)x, (const unsigned int*)tab, g);
    norm_kernel<<<1, 1024, 0, stream>>>(g, gamma, beta, out);
}